// Round 5
// baseline (364.303 us; speedup 1.0000x reference)
//
#include <hip/hip_runtime.h>

#define IN_DIM  256
#define OUT_DIM 128
#define B_ROWS  4096
#define N_COLS  8192
#define ALPHA   0.2f
#define NSP     4          // n-splits for k_attn

typedef unsigned short u16;
typedef unsigned int   u32;
typedef __attribute__((ext_vector_type(8))) short short8;
typedef __attribute__((ext_vector_type(4))) float floatx4;

__device__ __forceinline__ float bf2f(u16 v){ return __uint_as_float(((u32)v) << 16); }
__device__ __forceinline__ float bflo(u32 v){ return __uint_as_float(v << 16); }
__device__ __forceinline__ float bfhi(u32 v){ return __uint_as_float(v & 0xffff0000u); }
__device__ __forceinline__ u16 f2bf(float f){
    u32 u = __float_as_uint(f);
    u += 0x7fffu + ((u >> 16) & 1u);       // round-to-nearest-even
    return (u16)(u >> 16);
}

// wave-level dtype detect (no barrier): reads gf[0..255] words, L2-hot after first use.
// f32 N(0,1): bits7..14 ~uniform (~12% in [110,140]); bf16-pair: low-elem exponent (~97%).
__device__ __forceinline__ int detect_bf16_wave(const u32* __restrict__ g){
    int lane = threadIdx.x & 63;
    uint4 u = ((const uint4*)g)[lane];
#define CHK(x) ((((x) >> 7) & 0xFF) >= 110 && (((x) >> 7) & 0xFF) <= 140)
    unsigned long long c0 = __ballot(CHK(u.x)), c1 = __ballot(CHK(u.y));
    unsigned long long c2 = __ballot(CHK(u.z)), c3 = __ballot(CHK(u.w));
#undef CHK
    int votes = __popcll(c0) + __popcll(c1) + __popcll(c2) + __popcll(c3);
    return votes >= 128;
}

// ---- k_prep: WB (B-frag layout) + Wa1 = W@a1 + a2f. 32 blocks x 128 thr ----
__global__ __launch_bounds__(128) void k_prep(const void* __restrict__ gf,
                                              const void* __restrict__ W, const void* __restrict__ a1,
                                              const void* __restrict__ a2,
                                              u16* __restrict__ WB, float* __restrict__ Wa1,
                                              float* __restrict__ a2f){
    const int isbf = detect_bf16_wave((const u32*)gf);
    const int c  = threadIdx.x;
    const int kb = blockIdx.x;
    float a1c = isbf ? bf2f(((const u16*)a1)[c]) : ((const float*)a1)[c];
    float w[8]; short8 v;
#pragma unroll
    for (int j = 0; j < 8; j++){
        w[j] = isbf ? bf2f(((const u16*)W)[(kb*8 + j) * OUT_DIM + c])
                    : ((const float*)W)[(kb*8 + j) * OUT_DIM + c];
        v[j] = (short)f2bf(w[j]);
    }
    ((short8*)WB)[kb * OUT_DIM + c] = v;

    __shared__ float red[2][8];
    int lane = c & 63, wv = c >> 6;
#pragma unroll
    for (int j = 0; j < 8; j++){
        float p = w[j] * a1c;
        p += __shfl_xor(p, 1);  p += __shfl_xor(p, 2);  p += __shfl_xor(p, 4);
        p += __shfl_xor(p, 8);  p += __shfl_xor(p, 16); p += __shfl_xor(p, 32);
        if (lane == 0) red[wv][j] = p;
    }
    __syncthreads();
    if (c < 8) Wa1[kb*8 + c] = red[0][c] + red[1][c];
    if (kb == 0) a2f[c] = isbf ? bf2f(((const u16*)a2)[c]) : ((const float*)a2)[c];
}

// ---- h_neigh = gf[uniq]@W via MFMA -> hB blocked bf16 + s_neigh = h@a2 ----
// hB layout: u16 hB[(n>>3)*1024 + c*8 + (n&7)]
__global__ __launch_bounds__(256) void k_hneigh(const void* __restrict__ gf, const int* __restrict__ uniq,
                                                const u16* __restrict__ WB, const float* __restrict__ a2f,
                                                u16* __restrict__ hB, float* __restrict__ s_neigh){
    const int n0   = blockIdx.x * 16;
    const int t    = threadIdx.x;
    const int lane = t & 63;
    const int wv   = t >> 6;
    const int q    = lane >> 4;
    const int m    = lane & 15;
    const int isbf = detect_bf16_wave((const u32*)gf);
    const int jb0  = wv * 2;

    const size_t row = (size_t)uniq[n0 + m];
    const short8* wb8 = (const short8*)WB;

    floatx4 acc0 = {0.f,0.f,0.f,0.f};
    floatx4 acc1 = {0.f,0.f,0.f,0.f};

#pragma unroll
    for (int ks = 0; ks < IN_DIM/32; ks++){
        short8 afrag;
        if (isbf){
            afrag = *(const short8*)((const u16*)gf + row * IN_DIM + ks*32 + q*8);
        } else {
            const float* gp = (const float*)gf + row * IN_DIM + ks*32 + q*8;
            float4 f0 = *(const float4*)gp;
            float4 f1 = *(const float4*)(gp + 4);
            afrag[0] = (short)f2bf(f0.x); afrag[1] = (short)f2bf(f0.y);
            afrag[2] = (short)f2bf(f0.z); afrag[3] = (short)f2bf(f0.w);
            afrag[4] = (short)f2bf(f1.x); afrag[5] = (short)f2bf(f1.y);
            afrag[6] = (short)f2bf(f1.z); afrag[7] = (short)f2bf(f1.w);
        }
        const int kb = ks*4 + q;
        short8 b0 = wb8[kb * OUT_DIM + jb0*16 + m];
        short8 b1 = wb8[kb * OUT_DIM + (jb0+1)*16 + m];
        acc0 = __builtin_amdgcn_mfma_f32_16x16x32_bf16(afrag, b0, acc0, 0, 0, 0);
        acc1 = __builtin_amdgcn_mfma_f32_16x16x32_bf16(afrag, b1, acc1, 0, 0, 0);
    }

    {   // C-layout: row=q*4+reg (neighbor), col=jb*16+m
        u32 lo0 = (u32)f2bf(acc0[0]) | ((u32)f2bf(acc0[1]) << 16);
        u32 hi0 = (u32)f2bf(acc0[2]) | ((u32)f2bf(acc0[3]) << 16);
        u32 lo1 = (u32)f2bf(acc1[0]) | ((u32)f2bf(acc1[1]) << 16);
        u32 hi1 = (u32)f2bf(acc1[2]) | ((u32)f2bf(acc1[3]) << 16);
        uint2 v0; v0.x = lo0; v0.y = hi0;
        uint2 v1; v1.x = lo1; v1.y = hi1;
        u16* base = hB + (size_t)(n0/8 + (q>>1)) * 1024 + (q&1)*4;
        *(uint2*)(base + (jb0*16 + m) * 8)     = v0;
        *(uint2*)(base + ((jb0+1)*16 + m) * 8) = v1;
    }

    __shared__ float sred[4][16];
    float a2c0 = a2f[jb0*16 + m], a2c1 = a2f[(jb0+1)*16 + m];
#pragma unroll
    for (int reg = 0; reg < 4; reg++){
        float pr = acc0[reg]*a2c0 + acc1[reg]*a2c1;
        pr += __shfl_xor(pr, 1); pr += __shfl_xor(pr, 2);
        pr += __shfl_xor(pr, 4); pr += __shfl_xor(pr, 8);
        if (m == 0) sred[wv][q*4 + reg] = pr;
    }
    __syncthreads();
    if (t < 16) s_neigh[n0 + t] = sred[0][t] + sred[1][t] + sred[2][t] + sred[3][t];
}

// ---- main: out_part[split][b][c] = sum_{n in split} p(b,n) h[n][c] ----
// 512 blocks = 128 row-groups x 4 splits. 512 thr = 8 waves. Block: 32 rows x 128 cols x 2048 n.
// Wave: 256 n, staged per-wave in LDS (no barriers in K-loop). s_node computed inline.
__global__ __launch_bounds__(512, 4) void k_attn(const void* __restrict__ gf, const int* __restrict__ nodes,
                                                 const int* __restrict__ mask,
                                                 const float* __restrict__ Wa1,
                                                 const float* __restrict__ s_neigh,
                                                 const u16* __restrict__ hB,
                                                 float* __restrict__ out_part){
    const int bid   = blockIdx.x;
    const int split = bid & (NSP-1);
    const int b0    = (bid >> 2) * 32;
    const int t     = threadIdx.x;
    const int lane  = t & 63;
    const int wv    = t >> 6;
    const int q     = lane >> 4;
    const int m     = lane & 15;
    const int isbf  = detect_bf16_wave((const u32*)gf);

    __shared__ __align__(16) u16 p_tile[8][32][72];   // per-wave slice, 144B rows (16B-aligned)
    __shared__ float red[32][128];                    // 16 KB combine buffer
    __shared__ float snode[32];

    // zero red (float4 x2 per thread)
    {
        float4 z = {0.f,0.f,0.f,0.f};
        ((float4*)red)[t*2] = z; ((float4*)red)[t*2+1] = z;
    }

    // s_node for rows wv*4 .. wv*4+3
    {
        float4 wa = ((const float4*)Wa1)[lane];
#pragma unroll
        for (int r4 = 0; r4 < 4; r4++){
            int row = wv*4 + r4;
            size_t node = (size_t)nodes[b0 + row];
            float x0, x1, x2, x3;
            if (isbf){
                uint2 gg = ((const uint2*)((const u16*)gf + node * IN_DIM))[lane];
                x0 = bflo(gg.x); x1 = bfhi(gg.x); x2 = bflo(gg.y); x3 = bfhi(gg.y);
            } else {
                float4 gg = ((const float4*)((const float*)gf + node * IN_DIM))[lane];
                x0 = gg.x; x1 = gg.y; x2 = gg.z; x3 = gg.w;
            }
            float s = x0*wa.x + x1*wa.y + x2*wa.z + x3*wa.w;
            s += __shfl_xor(s, 1);  s += __shfl_xor(s, 2);  s += __shfl_xor(s, 4);
            s += __shfl_xor(s, 8);  s += __shfl_xor(s, 16); s += __shfl_xor(s, 32);
            if (lane == 0) snode[row] = s;
        }
    }
    __syncthreads();

    floatx4 accA[8], accB[8];
#pragma unroll
    for (int jb = 0; jb < 8; jb++){ floatx4 z = {0.f,0.f,0.f,0.f}; accA[jb] = z; accB[jb] = z; }

    const int nwave = split * (N_COLS/NSP) + wv * 256;
    const short8* hb8 = (const short8*)hB;

    for (int ch = 0; ch < 4; ch++){
        const int nbase = nwave + ch*64;
        // coalesced mask loads: instr i covers rows i*4+q', 64 n; 16 full lines each
        int4 mk[8];
#pragma unroll
        for (int i = 0; i < 8; i++)
            mk[i] = *(const int4*)(mask + (size_t)(b0 + i*4 + q) * N_COLS + nbase + m*4);
        float4 sg = *(const float4*)(s_neigh + nbase + m*4);

#pragma unroll
        for (int i = 0; i < 8; i++){
            float sn = snode[i*4 + q];
            float e0 = sn + sg.x, e1 = sn + sg.y, e2 = sn + sg.z, e3 = sn + sg.w;
            e0 = fmaxf(e0, ALPHA*e0); e1 = fmaxf(e1, ALPHA*e1);
            e2 = fmaxf(e2, ALPHA*e2); e3 = fmaxf(e3, ALPHA*e3);
            e0 = fminf(e0, 60.f); e1 = fminf(e1, 60.f);
            e2 = fminf(e2, 60.f); e3 = fminf(e3, 60.f);
            float p0 = mk[i].x > 0 ? __expf(e0) : 0.f;
            float p1 = mk[i].y > 0 ? __expf(e1) : 0.f;
            float p2 = mk[i].z > 0 ? __expf(e2) : 0.f;
            float p3 = mk[i].w > 0 ? __expf(e3) : 0.f;
            uint2 pv;
            pv.x = (u32)f2bf(p0) | ((u32)f2bf(p1) << 16);
            pv.y = (u32)f2bf(p2) | ((u32)f2bf(p3) << 16);
            *(uint2*)&p_tile[wv][i*4 + q][m*4] = pv;
        }
        // same-wave ds_write -> ds_read: lgkmcnt ordering only, no barrier
#pragma unroll
        for (int ks = 0; ks < 2; ks++){
            short8 aA = *(const short8*)&p_tile[wv][m]     [ks*32 + q*8];
            short8 aB = *(const short8*)&p_tile[wv][16 + m][ks*32 + q*8];
            const int kb = ((nbase + ks*32) >> 3) + q;
#pragma unroll
            for (int jb = 0; jb < 8; jb++){
                short8 bfr = hb8[kb * OUT_DIM + jb*16 + m];
                accA[jb] = __builtin_amdgcn_mfma_f32_16x16x32_bf16(aA, bfr, accA[jb], 0, 0, 0);
                accB[jb] = __builtin_amdgcn_mfma_f32_16x16x32_bf16(aB, bfr, accB[jb], 0, 0, 0);
            }
        }
    }

    // combine 8 waves via LDS float atomics (C-layout: row=q*4+reg, col=jb*16+m)
#pragma unroll
    for (int jb = 0; jb < 8; jb++)
#pragma unroll
        for (int reg = 0; reg < 4; reg++){
            atomicAdd(&red[q*4 + reg][jb*16 + m],      accA[jb][reg]);
            atomicAdd(&red[16 + q*4 + reg][jb*16 + m], accB[jb][reg]);
        }
    __syncthreads();

    float* op = out_part + ((size_t)split * B_ROWS + b0) * OUT_DIM;
    ((float4*)op)[t*2]   = ((float4*)red)[t*2];
    ((float4*)op)[t*2+1] = ((float4*)red)[t*2+1];
}

// ---- combine splits + L2 normalize -> out (dtype per detect) ----
__global__ __launch_bounds__(128) void k_norm(const float* __restrict__ out_part,
                                              const void* __restrict__ gf, void* __restrict__ out){
    const int isbf = detect_bf16_wave((const u32*)gf);
    const int b = blockIdx.x, c = threadIdx.x;
    float v = 0.f;
#pragma unroll
    for (int s = 0; s < NSP; s++)
        v += out_part[((size_t)s * B_ROWS + b) * OUT_DIM + c];
    float ss = v * v;
    for (int off = 32; off > 0; off >>= 1) ss += __shfl_down(ss, off);
    __shared__ float red[2];
    int lane = c & 63, wv = c >> 6;
    if (lane == 0) red[wv] = ss;
    __syncthreads();
    float tot = red[0] + red[1];
    float scale = 1.f / fmaxf(sqrtf(tot), 1e-12f);
    float o = v * scale;
    if (isbf) ((u16*)out)[(size_t)b * OUT_DIM + c] = f2bf(o);
    else      ((float*)out)[(size_t)b * OUT_DIM + c] = o;
}

extern "C" void kernel_launch(void* const* d_in, const int* in_sizes, int n_in,
                              void* d_out, int out_size, void* d_ws, size_t ws_size,
                              hipStream_t stream){
    const void* gf    = d_in[0];
    const int*  nodes = (const int*)d_in[1];
    const int*  uniq  = (const int*)d_in[2];
    const int*  mask  = (const int*)d_in[3];
    const void* W     = d_in[4];
    const void* a1    = d_in[5];
    const void* a2    = d_in[6];

    char* ws = (char*)d_ws;
    u16*   hB       = (u16*)ws;                                  // 2 MB
    u16*   WB       = (u16*)(ws + (2u<<20));                     // 64 KB
    float* s_neigh  = (float*)(ws + (2u<<20) + (64u<<10));       // 32 KB
    float* Wa1      = (float*)(ws + (2u<<20) + (96u<<10));       // 1 KB
    float* a2f      = (float*)(ws + (2u<<20) + (97u<<10));       // 512 B
    float* out_part = (float*)(ws + (2u<<20) + (128u<<10));      // 8 MB

    hipLaunchKernelGGL(k_prep,   dim3(32),          dim3(128), 0, stream, gf, W, a1, a2, WB, Wa1, a2f);
    hipLaunchKernelGGL(k_hneigh, dim3(N_COLS/16),   dim3(256), 0, stream, gf, uniq, WB, a2f, hB, s_neigh);
    hipLaunchKernelGGL(k_attn,   dim3((B_ROWS/32)*NSP), dim3(512), 0, stream, gf, nodes, mask, Wa1, s_neigh, hB, out_part);
    hipLaunchKernelGGL(k_norm,   dim3(B_ROWS),      dim3(128), 0, stream, out_part, gf, d_out);
}

// Round 6
// 332.619 us; speedup vs baseline: 1.0953x; 1.0953x over previous
//
#include <hip/hip_runtime.h>
#include <hip/hip_bf16.h>

#define IN_DIM  256
#define OUT_DIM 128
#define B_ROWS  4096
#define N_COLS  8192
#define ALPHA   0.2f
#define NS      4          // n-splits for k_attn

typedef unsigned short u16;
typedef unsigned int   u32;
typedef __attribute__((ext_vector_type(8))) short short8;
typedef __attribute__((ext_vector_type(4))) float floatx4;

__device__ __forceinline__ float bf2f(u16 v){ return __uint_as_float(((u32)v) << 16); }
__device__ __forceinline__ float bflo(u32 v){ return __uint_as_float(v << 16); }
__device__ __forceinline__ float bfhi(u32 v){ return __uint_as_float(v & 0xffff0000u); }
__device__ __forceinline__ u16 f2bf(float f){
    u32 u = __float_as_uint(f);
    u += 0x7fffu + ((u >> 16) & 1u);
    return (u16)(u >> 16);
}
__device__ __forceinline__ u32 pack_bf16(float a, float b){
    __hip_bfloat162 h = __float22bfloat162_rn(make_float2(a, b));   // v_cvt_pk_bf16_f32 on gfx950
    return *reinterpret_cast<u32*>(&h);
}

// wave-level dtype detect: f32 N(0,1): bits7..14 ~uniform (~12% in [110,140]); bf16-pair: ~97%.
__device__ __forceinline__ int detect_bf16_wave(const u32* __restrict__ g){
    int lane = threadIdx.x & 63;
    uint4 u = ((const uint4*)g)[lane];
#define CHK(x) ((((x) >> 7) & 0xFF) >= 110 && (((x) >> 7) & 0xFF) <= 140)
    unsigned long long c0 = __ballot(CHK(u.x)), c1 = __ballot(CHK(u.y));
    unsigned long long c2 = __ballot(CHK(u.z)), c3 = __ballot(CHK(u.w));
#undef CHK
    int votes = __popcll(c0) + __popcll(c1) + __popcll(c2) + __popcll(c3);
    return votes >= 128;
}

// ---- k_prep: WB (B-frag layout) + Wa1 = W@a1 + a2f ----
__global__ __launch_bounds__(128) void k_prep(const void* __restrict__ gf,
                                              const void* __restrict__ W, const void* __restrict__ a1,
                                              const void* __restrict__ a2,
                                              u16* __restrict__ WB, float* __restrict__ Wa1,
                                              float* __restrict__ a2f){
    const int isbf = detect_bf16_wave((const u32*)gf);
    const int c  = threadIdx.x;
    const int kb = blockIdx.x;
    float a1c = isbf ? bf2f(((const u16*)a1)[c]) : ((const float*)a1)[c];
    float w[8]; short8 v;
#pragma unroll
    for (int j = 0; j < 8; j++){
        w[j] = isbf ? bf2f(((const u16*)W)[(kb*8 + j) * OUT_DIM + c])
                    : ((const float*)W)[(kb*8 + j) * OUT_DIM + c];
        v[j] = (short)f2bf(w[j]);
    }
    ((short8*)WB)[kb * OUT_DIM + c] = v;

    __shared__ float red[2][8];
    int lane = c & 63, wv = c >> 6;
#pragma unroll
    for (int j = 0; j < 8; j++){
        float p = w[j] * a1c;
        p += __shfl_xor(p, 1);  p += __shfl_xor(p, 2);  p += __shfl_xor(p, 4);
        p += __shfl_xor(p, 8);  p += __shfl_xor(p, 16); p += __shfl_xor(p, 32);
        if (lane == 0) red[wv][j] = p;
    }
    __syncthreads();
    if (c < 8) Wa1[kb*8 + c] = red[0][c] + red[1][c];
    if (kb == 0) a2f[c] = isbf ? bf2f(((const u16*)a2)[c]) : ((const float*)a2)[c];
}

// ---- h_neigh = gf[uniq]@W via MFMA -> hB blocked bf16 + esg2[n] = (e^sg, e^{0.2 sg}) ----
// hB layout: u16 hB[(n>>3)*1024 + c*8 + (n&7)]
__global__ __launch_bounds__(256) void k_hneigh(const void* __restrict__ gf, const int* __restrict__ uniq,
                                                const u16* __restrict__ WB, const float* __restrict__ a2f,
                                                u16* __restrict__ hB, float2* __restrict__ esg2){
    const int n0   = blockIdx.x * 16;
    const int t    = threadIdx.x;
    const int lane = t & 63;
    const int wv   = t >> 6;
    const int q    = lane >> 4;
    const int m    = lane & 15;
    const int isbf = detect_bf16_wave((const u32*)gf);
    const int jb0  = wv * 2;

    const size_t row = (size_t)uniq[n0 + m];
    const short8* wb8 = (const short8*)WB;

    floatx4 acc0 = {0.f,0.f,0.f,0.f};
    floatx4 acc1 = {0.f,0.f,0.f,0.f};

#pragma unroll
    for (int ks = 0; ks < IN_DIM/32; ks++){
        short8 afrag;
        if (isbf){
            afrag = *(const short8*)((const u16*)gf + row * IN_DIM + ks*32 + q*8);
        } else {
            const float* gp = (const float*)gf + row * IN_DIM + ks*32 + q*8;
            float4 f0 = *(const float4*)gp;
            float4 f1 = *(const float4*)(gp + 4);
            afrag[0] = (short)f2bf(f0.x); afrag[1] = (short)f2bf(f0.y);
            afrag[2] = (short)f2bf(f0.z); afrag[3] = (short)f2bf(f0.w);
            afrag[4] = (short)f2bf(f1.x); afrag[5] = (short)f2bf(f1.y);
            afrag[6] = (short)f2bf(f1.z); afrag[7] = (short)f2bf(f1.w);
        }
        const int kb = ks*4 + q;
        short8 b0 = wb8[kb * OUT_DIM + jb0*16 + m];
        short8 b1 = wb8[kb * OUT_DIM + (jb0+1)*16 + m];
        acc0 = __builtin_amdgcn_mfma_f32_16x16x32_bf16(afrag, b0, acc0, 0, 0, 0);
        acc1 = __builtin_amdgcn_mfma_f32_16x16x32_bf16(afrag, b1, acc1, 0, 0, 0);
    }

    {   // C-layout: row=q*4+reg (neighbor), col=jb*16+m
        uint2 v0, v1;
        v0.x = (u32)f2bf(acc0[0]) | ((u32)f2bf(acc0[1]) << 16);
        v0.y = (u32)f2bf(acc0[2]) | ((u32)f2bf(acc0[3]) << 16);
        v1.x = (u32)f2bf(acc1[0]) | ((u32)f2bf(acc1[1]) << 16);
        v1.y = (u32)f2bf(acc1[2]) | ((u32)f2bf(acc1[3]) << 16);
        u16* base = hB + (size_t)(n0/8 + (q>>1)) * 1024 + (q&1)*4;
        *(uint2*)(base + (jb0*16 + m) * 8)     = v0;
        *(uint2*)(base + ((jb0+1)*16 + m) * 8) = v1;
    }

    __shared__ float sred[4][16];
    float a2c0 = a2f[jb0*16 + m], a2c1 = a2f[(jb0+1)*16 + m];
#pragma unroll
    for (int reg = 0; reg < 4; reg++){
        float pr = acc0[reg]*a2c0 + acc1[reg]*a2c1;
        pr += __shfl_xor(pr, 1); pr += __shfl_xor(pr, 2);
        pr += __shfl_xor(pr, 4); pr += __shfl_xor(pr, 8);
        if (m == 0) sred[wv][q*4 + reg] = pr;
    }
    __syncthreads();
    if (t < 16){
        float s = sred[0][t] + sred[1][t] + sred[2][t] + sred[3][t];
        s = fminf(fmaxf(s, -40.f), 40.f);
        esg2[n0 + t] = make_float2(__expf(s), __expf(ALPHA * s));
    }
}

// ---- esn2[b] = (e^sn, e^{0.2 sn}), sn = gf[nodes[b]] . Wa1 ----
__global__ __launch_bounds__(256) void k_esn(const void* __restrict__ gf, const int* __restrict__ nodes,
                                             const float* __restrict__ Wa1, float2* __restrict__ esn2){
    int lane = threadIdx.x & 63, wv = threadIdx.x >> 6;
    int b = blockIdx.x * 4 + wv;
    const int isbf = detect_bf16_wave((const u32*)gf);
    float4 wa = ((const float4*)Wa1)[lane];
    float x0, x1, x2, x3;
    if (isbf){
        uint2 gg = ((const uint2*)((const u16*)gf + (size_t)nodes[b] * IN_DIM))[lane];
        x0 = bflo(gg.x); x1 = bfhi(gg.x); x2 = bflo(gg.y); x3 = bfhi(gg.y);
    } else {
        float4 gg = ((const float4*)((const float*)gf + (size_t)nodes[b] * IN_DIM))[lane];
        x0 = gg.x; x1 = gg.y; x2 = gg.z; x3 = gg.w;
    }
    float s = x0*wa.x + x1*wa.y + x2*wa.z + x3*wa.w;
    s += __shfl_xor(s, 1);  s += __shfl_xor(s, 2);  s += __shfl_xor(s, 4);
    s += __shfl_xor(s, 8);  s += __shfl_xor(s, 16); s += __shfl_xor(s, 32);
    if (lane == 0){
        s = fminf(fmaxf(s, -40.f), 40.f);
        esn2[b] = make_float2(__expf(s), __expf(ALPHA * s));
    }
}

// ---- k_bits: mask int32 -> bitmask, pure stream (128 B contiguous per lane) ----
// bm[b][w] bit j = (mask[b][w*32+j] != 0)
__global__ __launch_bounds__(256) void k_bits(const int* __restrict__ mask, u32* __restrict__ bm){
    const size_t base = (size_t)blockIdx.x * N_COLS;       // one row per block
    const int t = threadIdx.x;
    const int4* m4 = (const int4*)(mask + base) + t*8;
    u32 b = 0;
#pragma unroll
    for (int i = 0; i < 8; i++){
        int4 v = m4[i];
        b |= (v.x != 0 ? 1u : 0u) << (i*4);
        b |= (v.y != 0 ? 1u : 0u) << (i*4+1);
        b |= (v.z != 0 ? 1u : 0u) << (i*4+2);
        b |= (v.w != 0 ? 1u : 0u) << (i*4+3);
    }
    bm[(size_t)blockIdx.x * (N_COLS/32) + t] = b;
}

// ---- main GEMM: out_part[ns][b][c] = sum_{n in ns} p(b,n) h[n][c] ----
// p = (t<1 ? esn02*esg02 : esn*esg) masked by bit;  t = esn*esg  (== exp(sn+sg))
// 512 blocks = 128 rowgroups x 4 nsplits. 512 thr = 8 waves = 2 rowtiles x 4 wave-nsplits.
// Wave: 16 rows x 512 n; mask words hoisted to 16 regs; no LDS in K-loop.
__global__ __launch_bounds__(512) void k_attn(const u32* __restrict__ bm,
                                              const float2* __restrict__ esn2,
                                              const float2* __restrict__ esg2,
                                              const u16* __restrict__ hB,
                                              float* __restrict__ out_part){
    const int bid = blockIdx.x;
    const int ns  = bid & (NS-1);
    const int b0  = (bid >> 2) * 32;
    const int t = threadIdx.x, lane = t & 63, wv = t >> 6;
    const int rt = wv & 1, wsp = wv >> 1;
    const int q = lane >> 4, m = lane & 15;
    const int row = b0 + rt*16 + m;
    const int n0  = ns*(N_COLS/NS) + wsp*512;

    __shared__ float red[32][128];          // 16 KB
    {
        float4 z4 = {0.f,0.f,0.f,0.f};
        ((float4*)red)[t*2] = z4; ((float4*)red)[t*2+1] = z4;
    }
    __syncthreads();

    const float2 en = esn2[row];

    // hoist this lane's 16 bitmask words (64 B contiguous)
    uint4 w4[4];
    {
        const uint4* bmr = (const uint4*)(bm + (size_t)row*(N_COLS/32) + (n0 >> 5));
#pragma unroll
        for (int i = 0; i < 4; i++) w4[i] = bmr[i];
    }
    u32 w16[16];
#pragma unroll
    for (int i = 0; i < 4; i++){
        w16[i*4+0] = w4[i].x; w16[i*4+1] = w4[i].y;
        w16[i*4+2] = w4[i].z; w16[i*4+3] = w4[i].w;
    }

    floatx4 acc[8];
#pragma unroll
    for (int jb = 0; jb < 8; jb++){ floatx4 z = {0.f,0.f,0.f,0.f}; acc[jb] = z; }

    const short8* hb8 = (const short8*)hB;

#pragma unroll
    for (int ks = 0; ks < 16; ks++){
        const int nn = n0 + ks*32;
        const u32 wq = w16[ks] >> (q*8);
        const float4* eg = (const float4*)esg2 + ((nn + q*8) >> 1);
        float4 g0 = eg[0], g1 = eg[1], g2 = eg[2], g3 = eg[3];

        float p[8];
#define PEL(j, gx, gy) { float tv = en.x * (gx); float t2 = en.y * (gy); \
                         float tt = (tv < 1.f) ? t2 : tv;                \
                         p[j] = (wq & (1u << (j))) ? tt : 0.f; }
        PEL(0, g0.x, g0.y) PEL(1, g0.z, g0.w)
        PEL(2, g1.x, g1.y) PEL(3, g1.z, g1.w)
        PEL(4, g2.x, g2.y) PEL(5, g2.z, g2.w)
        PEL(6, g3.x, g3.y) PEL(7, g3.z, g3.w)
#undef PEL
        uint4 av;
        av.x = pack_bf16(p[0], p[1]); av.y = pack_bf16(p[2], p[3]);
        av.z = pack_bf16(p[4], p[5]); av.w = pack_bf16(p[6], p[7]);
        short8 af = *reinterpret_cast<short8*>(&av);

        const int kb = (nn >> 3) + q;
#pragma unroll
        for (int jb = 0; jb < 8; jb++){
            short8 bfr = hb8[kb * OUT_DIM + jb*16 + m];
            acc[jb] = __builtin_amdgcn_mfma_f32_16x16x32_bf16(af, bfr, acc[jb], 0, 0, 0);
        }
    }

    // combine 4 n-split waves per rowtile (C-layout: row=q*4+reg, col=jb*16+m)
#pragma unroll
    for (int jb = 0; jb < 8; jb++)
#pragma unroll
        for (int reg = 0; reg < 4; reg++)
            atomicAdd(&red[rt*16 + q*4 + reg][jb*16 + m], acc[jb][reg]);
    __syncthreads();

    float* op = out_part + ((size_t)ns * B_ROWS + b0) * OUT_DIM;
    ((float4*)op)[t*2]   = ((float4*)red)[t*2];
    ((float4*)op)[t*2+1] = ((float4*)red)[t*2+1];
}

// ---- combine splits + L2 normalize -> out ----
__global__ __launch_bounds__(128) void k_norm(const float* __restrict__ out_part,
                                              const void* __restrict__ gf, void* __restrict__ out){
    const int isbf = detect_bf16_wave((const u32*)gf);
    const int b = blockIdx.x, c = threadIdx.x;
    float v = 0.f;
#pragma unroll
    for (int s = 0; s < NS; s++)
        v += out_part[((size_t)s * B_ROWS + b) * OUT_DIM + c];
    float ss = v * v;
    for (int off = 32; off > 0; off >>= 1) ss += __shfl_down(ss, off);
    __shared__ float red[2];
    int lane = c & 63, wv = c >> 6;
    if (lane == 0) red[wv] = ss;
    __syncthreads();
    float tot = red[0] + red[1];
    float scale = 1.f / fmaxf(sqrtf(tot), 1e-12f);
    float o = v * scale;
    if (isbf) ((u16*)out)[(size_t)b * OUT_DIM + c] = f2bf(o);
    else      ((float*)out)[(size_t)b * OUT_DIM + c] = o;
}

extern "C" void kernel_launch(void* const* d_in, const int* in_sizes, int n_in,
                              void* d_out, int out_size, void* d_ws, size_t ws_size,
                              hipStream_t stream){
    const void* gf    = d_in[0];
    const int*  nodes = (const int*)d_in[1];
    const int*  uniq  = (const int*)d_in[2];
    const int*  mask  = (const int*)d_in[3];
    const void* W     = d_in[4];
    const void* a1    = d_in[5];
    const void* a2    = d_in[6];

    char* ws = (char*)d_ws;
    u16*    hB       = (u16*)ws;                                 // 2 MB
    u16*    WB       = (u16*)(ws + (2u<<20));                    // 64 KB
    float2* esg2     = (float2*)(ws + (2u<<20) + (64u<<10));     // 64 KB
    float*  Wa1      = (float*)(ws + (2u<<20) + (128u<<10));     // 1 KB
    float*  a2f      = (float*)(ws + (2u<<20) + (129u<<10));     // 512 B
    float2* esn2     = (float2*)(ws + (2u<<20) + (130u<<10));    // 32 KB
    u32*    bm       = (u32*)(ws + (4u<<20));                    // 4 MB
    float*  out_part = (float*)(ws + (8u<<20));                  // 8 MB

    hipLaunchKernelGGL(k_prep,   dim3(32),            dim3(128), 0, stream, gf, W, a1, a2, WB, Wa1, a2f);
    hipLaunchKernelGGL(k_hneigh, dim3(N_COLS/16),     dim3(256), 0, stream, gf, uniq, WB, a2f, hB, esg2);
    hipLaunchKernelGGL(k_esn,    dim3(B_ROWS/4),      dim3(256), 0, stream, gf, nodes, Wa1, esn2);
    hipLaunchKernelGGL(k_bits,   dim3(B_ROWS),        dim3(256), 0, stream, mask, bm);
    hipLaunchKernelGGL(k_attn,   dim3((B_ROWS/32)*NS),dim3(512), 0, stream, bm, esn2, esg2, hB, out_part);
    hipLaunchKernelGGL(k_norm,   dim3(B_ROWS),        dim3(128), 0, stream, out_part, gf, d_out);
}